// Round 8
// baseline (1724.241 us; speedup 1.0000x reference)
//
#include <hip/hip_runtime.h>
#include <math.h>

#define BB 64
#define QQ 900
#define NN 30
#define C1 1001
#define NO_OBJ_W 0.1f

// ATTRIBUTION ROUND: in-kernel amplification reps (all idempotent)
#define COST_REPS 4
#define SEL_REPS 32
#define MATCH_REPS 64
#define LOSS_REPS 64

// ---- persistent device scratch (fully rewritten every call) ----
__device__ __align__(16) float g_CT[BB * NN * QQ];          // costs TRANSPOSED [b][t][q]
__device__ unsigned long long g_top[BB * NN * NN];          // per-column sorted top-30 keys
__device__ float  g_logZ[BB * QQ];                          // per-query logsumexp
__device__ float  g_noobj[BB * QQ];                         // per-query no-object nll
__device__ float4 g_xyxy[BB * QQ];                          // clipped pred boxes (xyxy)
__device__ int    g_pi[BB * NN];                            // matched query idx
__device__ int    g_ti[BB * NN];                            // matched target idx
__device__ float4 g_partial[BB];                            // per-batch (ce_num, l1, gl, _)

__device__ __forceinline__ float giou_f(float ax1, float ay1, float ax2, float ay2,
                                        float bx1, float by1, float bx2, float by2) {
    float ix1 = fmaxf(ax1, bx1), iy1 = fmaxf(ay1, by1);
    float ix2 = fminf(ax2, bx2), iy2 = fminf(ay2, by2);
    float iw = fmaxf(ix2 - ix1, 0.f), ih = fmaxf(iy2 - iy1, 0.f);
    float inter = iw * ih;
    float areaA = fmaxf(ax2 - ax1, 0.f) * fmaxf(ay2 - ay1, 0.f);
    float areaB = fmaxf(bx2 - bx1, 0.f) * fmaxf(by2 - by1, 0.f);
    float uni = areaA + areaB - inter;
    float iou = inter / fmaxf(uni, 1e-6f);
    float cx1 = fminf(ax1, bx1), cy1 = fminf(ay1, by1);
    float cx2 = fmaxf(ax2, bx2), cy2 = fmaxf(ay2, by2);
    float cw = fmaxf(cx2 - cx1, 0.f), ch = fmaxf(cy2 - cy1, 0.f);
    float ac = cw * ch;
    return iou - (ac - uni) / fmaxf(ac, 1e-6f);
}

__device__ __forceinline__ unsigned ord_map(float f) {
    unsigned u = __float_as_uint(f);
    return (u & 0x80000000u) ? ~u : (u | 0x80000000u);
}

// ---- K1: per-query softmax + TRANSPOSED cost write + noobj nll (x4) ----
__global__ __launch_bounds__(256) void cost_kernel(const float* __restrict__ logits,
                                                   const float* __restrict__ pboxes,
                                                   const int*   __restrict__ labels,
                                                   const float* __restrict__ tboxes) {
    int gwave = (blockIdx.x * blockDim.x + threadIdx.x) >> 6;
    int lane = threadIdx.x & 63;
    bool active = gwave < BB * QQ;
    int b = gwave / QQ;
    int q = gwave - b * QQ;

    for (int rep = 0; rep < COST_REPS; ++rep) {
        asm volatile("" ::: "memory");
        if (active) {
            size_t s = (size_t)gwave * C1;
            size_t a0 = (s + 3) >> 2;
            size_t a1 = (s + C1) >> 2;
            int nq = (int)(a1 - a0);
            int hh = (int)(a0 * 4 - s);
            int tt = (int)((s + C1) - a1 * 4);
            const float4* L4 = (const float4*)logits;

            float4 v4[4];
#pragma unroll
            for (int i = 0; i < 4; ++i) {
                int qq = lane + 64 * i;
                v4[i] = (qq < nq) ? L4[a0 + qq]
                                  : make_float4(-INFINITY, -INFINITY, -INFINITY, -INFINITY);
            }
            float e1 = (lane < hh) ? logits[s + lane] : -INFINITY;
            float e2 = (lane < tt) ? logits[a1 * 4 + lane] : -INFINITY;

            float mx = fmaxf(e1, e2);
#pragma unroll
            for (int i = 0; i < 4; ++i)
                mx = fmaxf(mx, fmaxf(fmaxf(v4[i].x, v4[i].y), fmaxf(v4[i].z, v4[i].w)));
#pragma unroll
            for (int off = 32; off; off >>= 1) mx = fmaxf(mx, __shfl_xor(mx, off));

            float sm = __expf(e1 - mx) + __expf(e2 - mx);
#pragma unroll
            for (int i = 0; i < 4; ++i) {
                sm += __expf(v4[i].x - mx);
                sm += __expf(v4[i].y - mx);
                sm += __expf(v4[i].z - mx);
                sm += __expf(v4[i].w - mx);
            }
#pragma unroll
            for (int off = 32; off; off >>= 1) sm += __shfl_xor(sm, off);
            float logZ = mx + __logf(sm);

            float row1000 = logits[s + 1000];

            const float* pb = pboxes + (size_t)gwave * 4;
            float cx = pb[0], cy = pb[1], w = pb[2], h = pb[3];
            float x1 = fminf(fmaxf(cx - 0.5f * w, 0.f), 1.f);
            float y1 = fminf(fmaxf(cy - 0.5f * h, 0.f), 1.f);
            float x2 = fminf(fmaxf(cx + 0.5f * w, 0.f), 1.f);
            float y2 = fminf(fmaxf(cy + 0.5f * h, 0.f), 1.f);

            if (lane == 0) {
                g_logZ[gwave] = logZ;
                g_noobj[gwave] = logZ - row1000;
                g_xyxy[gwave] = make_float4(x1, y1, x2, y2);
            }

            if (lane < NN) {
                int t = lane;
                int lab = labels[b * NN + t];
                float pcls = __expf(logits[s + lab] - logZ);
                const float* tb = tboxes + ((size_t)(b * NN + t)) * 4;
                float tx1 = tb[0], ty1 = tb[1], tx2 = tb[2], ty2 = tb[3];
                float l1 = fabsf(x1 - tx1) + fabsf(y1 - ty1) + fabsf(x2 - tx2) + fabsf(y2 - ty2);
                float g = giou_f(x1, y1, x2, y2, tx1, ty1, tx2, ty2);
                g_CT[((size_t)(b * NN + t)) * QQ + q] = -pcls + 5.0f * l1 - 2.0f * g;
            }
        }
    }
}

// ---- K2a: per-column sorted top-30 selection (one wave per (b,t)) (x32) ----
__global__ __launch_bounds__(256) void select_kernel() {
    int gw = (blockIdx.x * blockDim.x + threadIdx.x) >> 6;
    int lane = threadIdx.x & 63;
    bool active = gw < BB * NN;
    int t = gw % NN;

    for (int rep = 0; rep < SEL_REPS; ++rep) {
        asm volatile("" ::: "memory");
        if (active) {
            const float4* col4 = (const float4*)(g_CT + (size_t)gw * QQ);
            unsigned long long key[16];
#pragma unroll
            for (int k = 0; k < 4; ++k) {
                int f = lane + 64 * k;
                bool ok = f < 225;
                float4 v = ok ? col4[f] : make_float4(0.f, 0.f, 0.f, 0.f);
                int r0 = f * 4;
                key[4 * k + 0] = ok ? (((unsigned long long)ord_map(v.x) << 32) | (unsigned)((r0 + 0) * NN + t)) : ~0ull;
                key[4 * k + 1] = ok ? (((unsigned long long)ord_map(v.y) << 32) | (unsigned)((r0 + 1) * NN + t)) : ~0ull;
                key[4 * k + 2] = ok ? (((unsigned long long)ord_map(v.z) << 32) | (unsigned)((r0 + 2) * NN + t)) : ~0ull;
                key[4 * k + 3] = ok ? (((unsigned long long)ord_map(v.w) << 32) | (unsigned)((r0 + 3) * NN + t)) : ~0ull;
            }

            unsigned long long lm = key[0];
#pragma unroll
            for (int i = 1; i < 16; ++i) lm = (key[i] < lm) ? key[i] : lm;

            unsigned long long* outp = g_top + (size_t)gw * NN;
            for (int it = 0; it < NN; ++it) {
                unsigned long long g = lm;
#pragma unroll
                for (int off = 32; off; off >>= 1) {
                    unsigned long long o = __shfl_xor(g, off);
                    g = (o < g) ? o : g;
                }
                if (lane == it) outp[it] = g;
                if (lm == g) {
#pragma unroll
                    for (int i = 0; i < 16; ++i) key[i] = (key[i] == g) ? ~0ull : key[i];
                    lm = key[0];
#pragma unroll
                    for (int i = 1; i < 16; ++i) lm = (key[i] < lm) ? key[i] : lm;
                }
            }
        }
    }
}

// ---- K2b: greedy match on reduced 30x30 lists (one wave per batch) (x64) ----
__global__ __launch_bounds__(64) void match_kernel() {
    int b = blockIdx.x;
    int lane = threadIdx.x;

    __shared__ unsigned long long s_cand[NN * NN];
    __shared__ unsigned s_dead[29];

    for (int rep = 0; rep < MATCH_REPS; ++rep) {
        asm volatile("" ::: "memory");
        const unsigned long long* topb = g_top + (size_t)b * NN * NN;
#pragma unroll
        for (int k = 0; k < 15; ++k) {
            int i = lane + 64 * k;
            if (i < NN * NN) s_cand[i] = topb[i];
        }
        if (lane < 29) s_dead[lane] = 0u;

        bool colLive = lane < NN;
        int ptr = 0;
        unsigned long long cand = colLive ? s_cand[lane * NN] : ~0ull;
        unsigned rowc = colLive ? ((unsigned)cand) / NN : 0u;

        for (int it = 0; it < NN; ++it) {
            unsigned long long g = colLive ? cand : ~0ull;
#pragma unroll
            for (int off = 32; off; off >>= 1) {
                unsigned long long o = __shfl_xor(g, off);
                g = (o < g) ? o : g;
            }
            unsigned e = (unsigned)g;
            int pq = e / NN;
            int pt = e - pq * NN;
            if (lane == 0) {
                g_pi[b * NN + it] = pq;
                g_ti[b * NN + it] = pt;
                s_dead[pq >> 5] |= (1u << (pq & 31));
            }
            if (lane == pt) colLive = false;
            if (colLive && rowc == (unsigned)pq) {
                do {
                    ++ptr;
                    cand = s_cand[lane * NN + ptr];
                    rowc = ((unsigned)cand) / NN;
                } while ((s_dead[rowc >> 5] >> (rowc & 31)) & 1u);
            }
        }
    }
}

// ---- K3: per-batch losses (x64) ----
__global__ __launch_bounds__(256) void loss_kernel(const float* __restrict__ logits,
                                                   const int*   __restrict__ labels,
                                                   const float* __restrict__ tboxes) {
    int b = blockIdx.x;
    int tid = threadIdx.x;
    __shared__ float s4[4][4];

    for (int rep = 0; rep < LOSS_REPS; ++rep) {
        asm volatile("" ::: "memory");
        float sA = 0.f;
        for (int q = tid; q < QQ; q += 256) sA += g_noobj[b * QQ + q];

        float sB = 0.f, sL = 0.f, sG = 0.f;
        if (tid < NN) {
            int pq = g_pi[b * NN + tid], pt = g_ti[b * NN + tid];
            int gq = b * QQ + pq;
            int lab = labels[b * NN + pt];
            float mnll = g_logZ[gq] - logits[(size_t)gq * C1 + lab];
            sB = mnll - NO_OBJ_W * g_noobj[gq];
            float4 p = g_xyxy[gq];
            const float* tb = tboxes + ((size_t)(b * NN + pt)) * 4;
            float tx1 = tb[0], ty1 = tb[1], tx2 = tb[2], ty2 = tb[3];
            sL = fabsf(p.x - tx1) + fabsf(p.y - ty1) + fabsf(p.z - tx2) + fabsf(p.w - ty2);
            sG = 1.0f - giou_f(p.x, p.y, p.z, p.w, tx1, ty1, tx2, ty2);
        }

        int lane = tid & 63, wid = tid >> 6;
        float vv[4] = {sA, sB, sL, sG};
#pragma unroll
        for (int j = 0; j < 4; ++j) {
            float x = vv[j];
#pragma unroll
            for (int off = 32; off; off >>= 1) x += __shfl_xor(x, off);
            if (lane == 0) s4[wid][j] = x;
        }
        __syncthreads();
        if (tid == 0) {
            float a = 0.f, bs = 0.f, l = 0.f, g = 0.f;
            for (int w = 0; w < 4; ++w) { a += s4[w][0]; bs += s4[w][1]; l += s4[w][2]; g += s4[w][3]; }
            g_partial[b] = make_float4(NO_OBJ_W * a + bs, l, g, 0.f);
        }
        __syncthreads();   // protect s4 reuse across reps
    }
}

// ---- K4: reduce over batches ----
__global__ __launch_bounds__(64) void final_kernel(float* __restrict__ out) {
    int b = threadIdx.x;
    float4 p = g_partial[b];
    float ce = p.x, l1 = p.y, gl = p.z;
#pragma unroll
    for (int off = 32; off; off >>= 1) {
        ce += __shfl_xor(ce, off);
        l1 += __shfl_xor(l1, off);
        gl += __shfl_xor(gl, off);
    }
    if (b == 0) {
        ce /= (float)(BB * 117);
        l1 /= (float)(BB * NN * 4);
        gl /= (float)(BB * NN);
        out[0] = ce + 5.0f * l1 + 2.0f * gl;
        out[1] = ce;
        out[2] = l1;
        out[3] = gl;
    }
}

extern "C" void kernel_launch(void* const* d_in, const int* in_sizes, int n_in,
                              void* d_out, int out_size, void* d_ws, size_t ws_size,
                              hipStream_t stream) {
    const float* pred_logits = (const float*)d_in[0];
    const float* pred_boxes  = (const float*)d_in[1];
    const int*   tgt_labels  = (const int*)d_in[2];
    const float* tgt_boxes   = (const float*)d_in[3];
    float* out = (float*)d_out;

    cost_kernel<<<(BB * QQ) / 4, 256, 0, stream>>>(pred_logits, pred_boxes, tgt_labels, tgt_boxes);
    select_kernel<<<(BB * NN) / 4, 256, 0, stream>>>();
    match_kernel<<<BB, 64, 0, stream>>>();
    loss_kernel<<<BB, 256, 0, stream>>>(pred_logits, tgt_labels, tgt_boxes);
    final_kernel<<<1, 64, 0, stream>>>(out);
}

// Round 9
// 99.000 us; speedup vs baseline: 17.4166x; 17.4166x over previous
//
#include <hip/hip_runtime.h>
#include <math.h>

#define BB 64
#define QQ 900
#define NN 30
#define C1 1001
#define QN (QQ * NN)
#define NO_OBJ_W 0.1f

// ---- persistent device scratch (fully rewritten every call) ----
__device__ unsigned g_ord[BB * QN];                 // order-mapped cost keys [b][q][t]
__device__ unsigned long long g_top[BB * NN * NN];  // per-column sorted top-30 keys
__device__ float  g_logZ[BB * QQ];                  // per-query logsumexp
__device__ float  g_noobj[BB * QQ];                 // per-query no-object nll
__device__ float4 g_xyxy[BB * QQ];                  // clipped pred boxes (xyxy)
__device__ int    g_pi[BB * NN];                    // matched query idx
__device__ int    g_ti[BB * NN];                    // matched target idx
__device__ float4 g_partial[BB];                    // per-batch (ce_num, l1, gl, _)

__device__ __forceinline__ float giou_f(float ax1, float ay1, float ax2, float ay2,
                                        float bx1, float by1, float bx2, float by2) {
    float ix1 = fmaxf(ax1, bx1), iy1 = fmaxf(ay1, by1);
    float ix2 = fminf(ax2, bx2), iy2 = fminf(ay2, by2);
    float iw = fmaxf(ix2 - ix1, 0.f), ih = fmaxf(iy2 - iy1, 0.f);
    float inter = iw * ih;
    float areaA = fmaxf(ax2 - ax1, 0.f) * fmaxf(ay2 - ay1, 0.f);
    float areaB = fmaxf(bx2 - bx1, 0.f) * fmaxf(by2 - by1, 0.f);
    float uni = areaA + areaB - inter;
    float iou = inter / fmaxf(uni, 1e-6f);
    float cx1 = fminf(ax1, bx1), cy1 = fminf(ay1, by1);
    float cx2 = fmaxf(ax2, bx2), cy2 = fmaxf(ay2, by2);
    float cw = fmaxf(cx2 - cx1, 0.f), ch = fmaxf(cy2 - cy1, 0.f);
    float ac = cw * ch;
    return iou - (ac - uni) / fmaxf(ac, 1e-6f);
}

__device__ __forceinline__ unsigned ord_map(float f) {
    unsigned u = __float_as_uint(f);
    return (u & 0x80000000u) ? ~u : (u | 0x80000000u);   // order-preserving map
}

// ---- K1: per-query softmax + contiguous ord-key write (R3 layout, measured 48us) ----
__global__ __launch_bounds__(256) void cost_kernel(const float* __restrict__ logits,
                                                   const float* __restrict__ pboxes,
                                                   const int*   __restrict__ labels,
                                                   const float* __restrict__ tboxes) {
    int gwave = (blockIdx.x * blockDim.x + threadIdx.x) >> 6;
    int lane = threadIdx.x & 63;
    if (gwave >= BB * QQ) return;
    int b = gwave / QQ;

    size_t s = (size_t)gwave * C1;
    size_t a0 = (s + 3) >> 2;
    size_t a1 = (s + C1) >> 2;
    int nq = (int)(a1 - a0);
    int hh = (int)(a0 * 4 - s);
    int tt = (int)((s + C1) - a1 * 4);
    const float4* L4 = (const float4*)logits;

    float4 v4[4];
#pragma unroll
    for (int i = 0; i < 4; ++i) {
        int qq = lane + 64 * i;
        v4[i] = (qq < nq) ? L4[a0 + qq]
                          : make_float4(-INFINITY, -INFINITY, -INFINITY, -INFINITY);
    }
    float e1 = (lane < hh) ? logits[s + lane] : -INFINITY;
    float e2 = (lane < tt) ? logits[a1 * 4 + lane] : -INFINITY;

    float mx = fmaxf(e1, e2);
#pragma unroll
    for (int i = 0; i < 4; ++i)
        mx = fmaxf(mx, fmaxf(fmaxf(v4[i].x, v4[i].y), fmaxf(v4[i].z, v4[i].w)));
#pragma unroll
    for (int off = 32; off; off >>= 1) mx = fmaxf(mx, __shfl_xor(mx, off));

    float sm = __expf(e1 - mx) + __expf(e2 - mx);
#pragma unroll
    for (int i = 0; i < 4; ++i) {
        sm += __expf(v4[i].x - mx);
        sm += __expf(v4[i].y - mx);
        sm += __expf(v4[i].z - mx);
        sm += __expf(v4[i].w - mx);
    }
#pragma unroll
    for (int off = 32; off; off >>= 1) sm += __shfl_xor(sm, off);
    float logZ = mx + __logf(sm);

    float row1000 = logits[s + 1000];

    const float* pb = pboxes + (size_t)gwave * 4;
    float cx = pb[0], cy = pb[1], w = pb[2], h = pb[3];
    float x1 = fminf(fmaxf(cx - 0.5f * w, 0.f), 1.f);
    float y1 = fminf(fmaxf(cy - 0.5f * h, 0.f), 1.f);
    float x2 = fminf(fmaxf(cx + 0.5f * w, 0.f), 1.f);
    float y2 = fminf(fmaxf(cy + 0.5f * h, 0.f), 1.f);

    if (lane == 0) {
        g_logZ[gwave] = logZ;
        g_noobj[gwave] = logZ - row1000;
        g_xyxy[gwave] = make_float4(x1, y1, x2, y2);
    }

    if (lane < NN) {
        int t = lane;
        int lab = labels[b * NN + t];
        float pcls = __expf(logits[s + lab] - logZ);
        const float* tb = tboxes + ((size_t)(b * NN + t)) * 4;
        float tx1 = tb[0], ty1 = tb[1], tx2 = tb[2], ty2 = tb[3];
        float l1 = fabsf(x1 - tx1) + fabsf(y1 - ty1) + fabsf(x2 - tx2) + fabsf(y2 - ty2);
        float g = giou_f(x1, y1, x2, y2, tx1, ty1, tx2, ty2);
        g_ord[(size_t)gwave * NN + t] = ord_map(-pcls + 5.0f * l1 - 2.0f * g);
    }
}

// ---- K2a: per-column sorted top-30 (one wave per (b,t)) ----
// lanes 0-59 each: 15 column values -> register bitonic-16 sort (static idx)
// -> sorted list to LDS -> 30 rounds of {u64 shfl-min + owner head-advance}.
__global__ __launch_bounds__(256) void select_kernel() {
    int gw = (blockIdx.x * blockDim.x + threadIdx.x) >> 6;   // (b,t)
    int lane = threadIdx.x & 63;
    int wid = (threadIdx.x >> 6) & 3;
    if (gw >= BB * NN) return;
    int b = gw / NN;
    int t = gw - b * NN;

    __shared__ unsigned long long s_ls[4][960];   // per-wave sorted lists, 30.7 KB

    unsigned long long key[16];
    if (lane < 60) {
#pragma unroll
        for (int j = 0; j < 15; ++j) {
            int q = j * 60 + lane;
            unsigned o = g_ord[((size_t)(b * QQ + q)) * NN + t];
            key[j] = ((unsigned long long)o << 32) | (unsigned)(q * NN + t);
        }
    } else {
#pragma unroll
        for (int j = 0; j < 15; ++j) key[j] = ~0ull;
    }
    key[15] = ~0ull;

    // bitonic sort 16 (ascending), fully static indices
#pragma unroll
    for (int kk = 2; kk <= 16; kk <<= 1) {
#pragma unroll
        for (int jj = kk >> 1; jj > 0; jj >>= 1) {
#pragma unroll
            for (int i = 0; i < 16; ++i) {
                int l = i ^ jj;
                if (l > i) {
                    bool up = ((i & kk) == 0);
                    unsigned long long a = key[i], c = key[l];
                    bool sw = up ? (a > c) : (a < c);
                    key[i] = sw ? c : a;
                    key[l] = sw ? a : c;
                }
            }
        }
    }

#pragma unroll
    for (int j = 0; j < 15; ++j) s_ls[wid][j * 64 + lane] = key[j];

    unsigned long long h = key[0];   // head value
    int p = 0;                       // head pointer
    unsigned long long* outp = g_top + (size_t)gw * NN;
    for (int it = 0; it < NN; ++it) {
        unsigned long long m = h;
#pragma unroll
        for (int off = 32; off; off >>= 1) {
            unsigned long long o = __shfl_xor(m, off);
            m = (o < m) ? o : m;
        }
        if (lane == it) outp[it] = m;       // sorted ascending
        if (h == m) {                        // unique owner (flat idx unique)
            ++p;
            h = (p < 15) ? s_ls[wid][p * 64 + lane] : ~0ull;
        }
    }
}

// ---- K2b: greedy match on reduced 30x30 lists (one wave per batch) ----
__global__ __launch_bounds__(64) void match_kernel() {
    int b = blockIdx.x;
    int lane = threadIdx.x;

    __shared__ unsigned long long s_cand[NN * NN];
    __shared__ unsigned s_dead[29];

    const unsigned long long* topb = g_top + (size_t)b * NN * NN;
#pragma unroll
    for (int k = 0; k < 15; ++k) {
        int i = lane + 64 * k;
        if (i < NN * NN) s_cand[i] = topb[i];
    }
    if (lane < 29) s_dead[lane] = 0u;

    bool colLive = lane < NN;
    int ptr = 0;
    unsigned long long cand = colLive ? s_cand[lane * NN] : ~0ull;
    unsigned rowc = colLive ? ((unsigned)cand) / NN : 0u;

    for (int it = 0; it < NN; ++it) {
        unsigned long long g = colLive ? cand : ~0ull;
#pragma unroll
        for (int off = 32; off; off >>= 1) {
            unsigned long long o = __shfl_xor(g, off);
            g = (o < g) ? o : g;
        }
        unsigned e = (unsigned)g;
        int pq = e / NN;
        int pt = e - pq * NN;
        if (lane == 0) {
            g_pi[b * NN + it] = pq;
            g_ti[b * NN + it] = pt;
            s_dead[pq >> 5] |= (1u << (pq & 31));
        }
        if (lane == pt) colLive = false;
        if (colLive && rowc == (unsigned)pq) {
            do {
                ++ptr;
                cand = s_cand[lane * NN + ptr];
                rowc = ((unsigned)cand) / NN;
            } while ((s_dead[rowc >> 5] >> (rowc & 31)) & 1u);
        }
    }
}

// ---- K3: per-batch losses (CE algebra: denom == 117 exactly) ----
__global__ __launch_bounds__(256) void loss_kernel(const float* __restrict__ logits,
                                                   const int*   __restrict__ labels,
                                                   const float* __restrict__ tboxes) {
    int b = blockIdx.x;
    int tid = threadIdx.x;

    float sA = 0.f;
    for (int q = tid; q < QQ; q += 256) sA += g_noobj[b * QQ + q];

    float sB = 0.f, sL = 0.f, sG = 0.f;
    if (tid < NN) {
        int pq = g_pi[b * NN + tid], pt = g_ti[b * NN + tid];
        int gq = b * QQ + pq;
        int lab = labels[b * NN + pt];
        float mnll = g_logZ[gq] - logits[(size_t)gq * C1 + lab];
        sB = mnll - NO_OBJ_W * g_noobj[gq];
        float4 p = g_xyxy[gq];
        const float* tb = tboxes + ((size_t)(b * NN + pt)) * 4;
        float tx1 = tb[0], ty1 = tb[1], tx2 = tb[2], ty2 = tb[3];
        sL = fabsf(p.x - tx1) + fabsf(p.y - ty1) + fabsf(p.z - tx2) + fabsf(p.w - ty2);
        sG = 1.0f - giou_f(p.x, p.y, p.z, p.w, tx1, ty1, tx2, ty2);
    }

    __shared__ float s4[4][4];
    int lane = tid & 63, wid = tid >> 6;
    float vv[4] = {sA, sB, sL, sG};
#pragma unroll
    for (int j = 0; j < 4; ++j) {
        float x = vv[j];
#pragma unroll
        for (int off = 32; off; off >>= 1) x += __shfl_xor(x, off);
        if (lane == 0) s4[wid][j] = x;
    }
    __syncthreads();
    if (tid == 0) {
        float a = 0.f, bs = 0.f, l = 0.f, g = 0.f;
        for (int w = 0; w < 4; ++w) { a += s4[w][0]; bs += s4[w][1]; l += s4[w][2]; g += s4[w][3]; }
        g_partial[b] = make_float4(NO_OBJ_W * a + bs, l, g, 0.f);
    }
}

// ---- K4: reduce over batches ----
__global__ __launch_bounds__(64) void final_kernel(float* __restrict__ out) {
    int b = threadIdx.x;
    float4 p = g_partial[b];
    float ce = p.x, l1 = p.y, gl = p.z;
#pragma unroll
    for (int off = 32; off; off >>= 1) {
        ce += __shfl_xor(ce, off);
        l1 += __shfl_xor(l1, off);
        gl += __shfl_xor(gl, off);
    }
    if (b == 0) {
        ce /= (float)(BB * 117);
        l1 /= (float)(BB * NN * 4);
        gl /= (float)(BB * NN);
        out[0] = ce + 5.0f * l1 + 2.0f * gl;
        out[1] = ce;
        out[2] = l1;
        out[3] = gl;
    }
}

extern "C" void kernel_launch(void* const* d_in, const int* in_sizes, int n_in,
                              void* d_out, int out_size, void* d_ws, size_t ws_size,
                              hipStream_t stream) {
    const float* pred_logits = (const float*)d_in[0];
    const float* pred_boxes  = (const float*)d_in[1];
    const int*   tgt_labels  = (const int*)d_in[2];
    const float* tgt_boxes   = (const float*)d_in[3];
    float* out = (float*)d_out;

    cost_kernel<<<(BB * QQ) / 4, 256, 0, stream>>>(pred_logits, pred_boxes, tgt_labels, tgt_boxes);
    select_kernel<<<(BB * NN) / 4, 256, 0, stream>>>();
    match_kernel<<<BB, 64, 0, stream>>>();
    loss_kernel<<<BB, 256, 0, stream>>>(pred_logits, tgt_labels, tgt_boxes);
    final_kernel<<<1, 64, 0, stream>>>(out);
}